// Round 4
// baseline (158.372 us; speedup 1.0000x reference)
//
#include <hip/hip_runtime.h>
#include <math.h>

// 32 nodes/block, 4 blocks/CU. Row-major LDS activations [node][feature].
// GEMM tiles are col-wide/row-narrow (2x8, 1x8, 1x4) so per-CU LDS-read
// cycles < FMA-issue cycles (round-1/2 were LDS-bound with tall tiles).
// Weights: vector float4 loads from L1 (vmcnt) -- NEVER scalar loads mixed
// with DS reads in a loop (round-3 lgkmcnt-drain disaster).
constexpr int SV  = 100;  // V  [32][96]
constexpr int SC  = 132;  // C  [32][128]
constexpr int SH1 = 68;   // H1 [32][64]
constexpr int SH2 = 36;   // H2 [32][32]
constexpr int SH3 = 20;   // H3 [32][16]

__global__ __launch_bounds__(256, 4)
void flatnet_fused(const float* __restrict__ pgi,
                   const float* __restrict__ Wl, const float* __restrict__ bl,
                   const float* __restrict__ Wc, const float* __restrict__ bc,
                   const float* __restrict__ W1, const float* __restrict__ b1,
                   const float* __restrict__ W2, const float* __restrict__ b2,
                   const float* __restrict__ W3, const float* __restrict__ b3,
                   const float* __restrict__ W4, const float* __restrict__ b4,
                   float* __restrict__ out)
{
    __shared__ float sA[32 * SV];   // V  -> H1 -> H3
    __shared__ float sB[32 * SC];   // C  -> H2

    const int t   = threadIdx.x;
    const int blk = blockIdx.x;

    // ===== Phase 0: lift (3->32) + ring-group max (pre-act), leaky after =====
    // 8 threads/node: q&3 = dim-quarter, q>>2 = mirrored row-half (GT[7-r]==GT[r]).
    {
        const int ln = t >> 3;          // local node 0..31
        const int q  = t & 7;
        const int dq = (q & 3) * 8;
        const int h  = q >> 2;
        const int gn = blk * 32 + ln;
        const int b  = gn >> 10;
        const int g  = gn & 1023;
        const int gi = g >> 5, gj = g & 31;

        float w0[8], w1[8], w2[8], bb[8];
        #pragma unroll
        for (int d = 0; d < 8; ++d) {
            w0[d] = Wl[dq + d];
            w1[d] = Wl[32 + dq + d];
            w2[d] = Wl[64 + dq + d];
            bb[d] = bl[dq + d];
        }

        float gm[3][8];
        #pragma unroll
        for (int gg = 0; gg < 3; ++gg)
            #pragma unroll
            for (int d = 0; d < 8; ++d) gm[gg][d] = -INFINITY;

        constexpr int GT4[4][8] = {
            {2,2,2,2,2,2,2,2},
            {2,2,2,2,2,2,2,2},
            {2,2,1,1,1,1,2,2},
            {2,2,1,0,0,1,2,2},
        };

        const size_t rowbase = (size_t)b * 65536 + ((size_t)gi * 8) * 256 + (size_t)gj * 8;
        #pragma unroll
        for (int pi = 0; pi < 4; ++pi) {
            const int prow = h ? (7 - pi) : pi;
            const float4* src = (const float4*)(pgi + (rowbase + (size_t)prow * 256) * 3);
            float f[24];
            #pragma unroll
            for (int l = 0; l < 6; ++l) {
                const float4 v = src[l];
                f[l*4+0] = v.x; f[l*4+1] = v.y; f[l*4+2] = v.z; f[l*4+3] = v.w;
            }
            #pragma unroll
            for (int pj = 0; pj < 8; ++pj) {
                const int grp = GT4[pi][pj];
                const float x = f[pj*3], y = f[pj*3+1], z = f[pj*3+2];
                #pragma unroll
                for (int d = 0; d < 8; ++d) {
                    float v = fmaf(x, w0[d], bb[d]);
                    v = fmaf(y, w1[d], v);
                    v = fmaf(z, w2[d], v);
                    gm[grp][d] = fmaxf(gm[grp][d], v);
                }
            }
        }
        #pragma unroll
        for (int gg = 0; gg < 3; ++gg)
            #pragma unroll
            for (int d = 0; d < 8; ++d)
                gm[gg][d] = fmaxf(gm[gg][d], __shfl_xor(gm[gg][d], 4));

        if (h == 0) {
            #pragma unroll
            for (int gg = 0; gg < 3; ++gg) {
                float4 lo, hi;
                lo.x = fmaxf(gm[gg][0], 0.2f*gm[gg][0]);
                lo.y = fmaxf(gm[gg][1], 0.2f*gm[gg][1]);
                lo.z = fmaxf(gm[gg][2], 0.2f*gm[gg][2]);
                lo.w = fmaxf(gm[gg][3], 0.2f*gm[gg][3]);
                hi.x = fmaxf(gm[gg][4], 0.2f*gm[gg][4]);
                hi.y = fmaxf(gm[gg][5], 0.2f*gm[gg][5]);
                hi.z = fmaxf(gm[gg][6], 0.2f*gm[gg][6]);
                hi.w = fmaxf(gm[gg][7], 0.2f*gm[gg][7]);
                *(float4*)&sA[ln*SV + gg*32 + dq]     = lo;
                *(float4*)&sA[ln*SV + gg*32 + dq + 4] = hi;
            }
        }
    }
    __syncthreads();

    // ===== Phase 1: C = leaky(V[32,96] @ Wc[96,128] + bc); tile 2 rows x 8 cols =====
    {
        const int r0 = (t >> 4) << 1;   // rows r0, r0+1
        const int c0 = (t & 15) << 3;   // cols c0..c0+7
        float acc[2][8];
        {
            const float4 b0 = *(const float4*)&bc[c0];
            const float4 b1 = *(const float4*)&bc[c0+4];
            #pragma unroll
            for (int r = 0; r < 2; ++r) {
                acc[r][0]=b0.x; acc[r][1]=b0.y; acc[r][2]=b0.z; acc[r][3]=b0.w;
                acc[r][4]=b1.x; acc[r][5]=b1.y; acc[r][6]=b1.z; acc[r][7]=b1.w;
            }
        }
        #pragma unroll 2
        for (int j = 0; j < 96; j += 4) {
            const float4 A0 = *(const float4*)&sA[ r0   *SV + j];
            const float4 A1 = *(const float4*)&sA[(r0+1)*SV + j];
            const float a0f[4] = {A0.x, A0.y, A0.z, A0.w};
            const float a1f[4] = {A1.x, A1.y, A1.z, A1.w};
            #pragma unroll
            for (int jj = 0; jj < 4; ++jj) {
                const float4 w0 = *(const float4*)&Wc[(j+jj)*128 + c0];
                const float4 w1 = *(const float4*)&Wc[(j+jj)*128 + c0 + 4];
                const float wv[8] = {w0.x,w0.y,w0.z,w0.w,w1.x,w1.y,w1.z,w1.w};
                #pragma unroll
                for (int c = 0; c < 8; ++c) {
                    acc[0][c] = fmaf(a0f[jj], wv[c], acc[0][c]);
                    acc[1][c] = fmaf(a1f[jj], wv[c], acc[1][c]);
                }
            }
        }
        #pragma unroll
        for (int r = 0; r < 2; ++r) {
            float4 lo, hi;
            lo.x = fmaxf(acc[r][0], 0.2f*acc[r][0]);
            lo.y = fmaxf(acc[r][1], 0.2f*acc[r][1]);
            lo.z = fmaxf(acc[r][2], 0.2f*acc[r][2]);
            lo.w = fmaxf(acc[r][3], 0.2f*acc[r][3]);
            hi.x = fmaxf(acc[r][4], 0.2f*acc[r][4]);
            hi.y = fmaxf(acc[r][5], 0.2f*acc[r][5]);
            hi.z = fmaxf(acc[r][6], 0.2f*acc[r][6]);
            hi.w = fmaxf(acc[r][7], 0.2f*acc[r][7]);
            *(float4*)&sB[(r0+r)*SC + c0]     = lo;
            *(float4*)&sB[(r0+r)*SC + c0 + 4] = hi;
        }
    }
    __syncthreads();

    // ===== Phase 2: H1 = relu(C[32,128] @ W1[128,64] + b1); tile 1 x 8 =====
    {
        const int r  = t >> 3;          // 0..31
        const int c0 = (t & 7) << 3;    // cols c0..c0+7
        float acc[8];
        {
            const float4 b0 = *(const float4*)&b1[c0];
            const float4 b1v = *(const float4*)&b1[c0+4];
            acc[0]=b0.x; acc[1]=b0.y; acc[2]=b0.z; acc[3]=b0.w;
            acc[4]=b1v.x; acc[5]=b1v.y; acc[6]=b1v.z; acc[7]=b1v.w;
        }
        #pragma unroll 2
        for (int j = 0; j < 128; j += 4) {
            const float4 A = *(const float4*)&sB[r*SC + j];
            const float af[4] = {A.x, A.y, A.z, A.w};
            #pragma unroll
            for (int jj = 0; jj < 4; ++jj) {
                const float4 w0 = *(const float4*)&W1[(j+jj)*64 + c0];
                const float4 w1 = *(const float4*)&W1[(j+jj)*64 + c0 + 4];
                const float wv[8] = {w0.x,w0.y,w0.z,w0.w,w1.x,w1.y,w1.z,w1.w};
                #pragma unroll
                for (int c = 0; c < 8; ++c)
                    acc[c] = fmaf(af[jj], wv[c], acc[c]);
            }
        }
        float4 lo, hi;
        lo.x = fmaxf(acc[0], 0.f); lo.y = fmaxf(acc[1], 0.f);
        lo.z = fmaxf(acc[2], 0.f); lo.w = fmaxf(acc[3], 0.f);
        hi.x = fmaxf(acc[4], 0.f); hi.y = fmaxf(acc[5], 0.f);
        hi.z = fmaxf(acc[6], 0.f); hi.w = fmaxf(acc[7], 0.f);
        *(float4*)&sA[r*SH1 + c0]     = lo;
        *(float4*)&sA[r*SH1 + c0 + 4] = hi;
    }
    __syncthreads();

    // ===== Phase 3: H2 = relu(H1[32,64] @ W2[64,32] + b2); tile 1 x 4 =====
    {
        const int r  = t >> 3;          // 0..31
        const int c0 = (t & 7) << 2;    // cols c0..c0+3
        float acc[4];
        {
            const float4 bv = *(const float4*)&b2[c0];
            acc[0]=bv.x; acc[1]=bv.y; acc[2]=bv.z; acc[3]=bv.w;
        }
        #pragma unroll 4
        for (int j = 0; j < 64; j += 4) {
            const float4 A = *(const float4*)&sA[r*SH1 + j];
            const float af[4] = {A.x, A.y, A.z, A.w};
            #pragma unroll
            for (int jj = 0; jj < 4; ++jj) {
                const float4 w = *(const float4*)&W2[(j+jj)*32 + c0];
                acc[0] = fmaf(af[jj], w.x, acc[0]);
                acc[1] = fmaf(af[jj], w.y, acc[1]);
                acc[2] = fmaf(af[jj], w.z, acc[2]);
                acc[3] = fmaf(af[jj], w.w, acc[3]);
            }
        }
        float4 o;
        o.x = fmaxf(acc[0], 0.f); o.y = fmaxf(acc[1], 0.f);
        o.z = fmaxf(acc[2], 0.f); o.w = fmaxf(acc[3], 0.f);
        *(float4*)&sB[r*SH2 + c0] = o;
    }
    __syncthreads();

    // ===== Phase 4: H3 = relu(H2[32,32] @ W3[32,16] + b3); 128 threads, 1 x 4 =====
    if (t < 128) {
        const int r  = t >> 2;          // 0..31
        const int c0 = (t & 3) << 2;    // cols c0..c0+3
        float acc[4];
        {
            const float4 bv = *(const float4*)&b3[c0];
            acc[0]=bv.x; acc[1]=bv.y; acc[2]=bv.z; acc[3]=bv.w;
        }
        #pragma unroll
        for (int j = 0; j < 32; j += 4) {
            const float4 A = *(const float4*)&sB[r*SH2 + j];
            const float af[4] = {A.x, A.y, A.z, A.w};
            #pragma unroll
            for (int jj = 0; jj < 4; ++jj) {
                const float4 w = *(const float4*)&W3[(j+jj)*16 + c0];
                acc[0] = fmaf(af[jj], w.x, acc[0]);
                acc[1] = fmaf(af[jj], w.y, acc[1]);
                acc[2] = fmaf(af[jj], w.z, acc[2]);
                acc[3] = fmaf(af[jj], w.w, acc[3]);
            }
        }
        float4 o;
        o.x = fmaxf(acc[0], 0.f); o.y = fmaxf(acc[1], 0.f);
        o.z = fmaxf(acc[2], 0.f); o.w = fmaxf(acc[3], 0.f);
        *(float4*)&sA[r*SH3 + c0] = o;
    }
    __syncthreads();

    // ===== Phase 5: out = H3[32,16] @ W4[16,3] + b4; 32 threads =====
    if (t < 32) {
        float acc0 = b4[0], acc1 = b4[1], acc2 = b4[2];
        float a[16];
        #pragma unroll
        for (int l = 0; l < 4; ++l) {
            const float4 v = *(const float4*)&sA[t*SH3 + l*4];
            a[l*4+0]=v.x; a[l*4+1]=v.y; a[l*4+2]=v.z; a[l*4+3]=v.w;
        }
        #pragma unroll
        for (int j = 0; j < 16; ++j) {
            acc0 = fmaf(a[j], W4[j*3+0], acc0);
            acc1 = fmaf(a[j], W4[j*3+1], acc1);
            acc2 = fmaf(a[j], W4[j*3+2], acc2);
        }
        const size_t gn = (size_t)blk * 32 + t;
        out[gn*3 + 0] = acc0;
        out[gn*3 + 1] = acc1;
        out[gn*3 + 2] = acc2;
    }
}

extern "C" void kernel_launch(void* const* d_in, const int* in_sizes, int n_in,
                              void* d_out, int out_size, void* d_ws, size_t ws_size,
                              hipStream_t stream)
{
    const float* pgi = (const float*)d_in[0];
    const float* Wl  = (const float*)d_in[1];
    const float* bl  = (const float*)d_in[2];
    const float* Wc  = (const float*)d_in[3];
    const float* bc  = (const float*)d_in[4];
    const float* W1  = (const float*)d_in[5];
    const float* b1  = (const float*)d_in[6];
    const float* W2  = (const float*)d_in[7];
    const float* b2  = (const float*)d_in[8];
    const float* W3  = (const float*)d_in[9];
    const float* b3  = (const float*)d_in[10];
    const float* W4  = (const float*)d_in[11];
    const float* b4  = (const float*)d_in[12];

    hipLaunchKernelGGL(flatnet_fused, dim3(1024), dim3(256), 0, stream,
                       pgi, Wl, bl, Wc, bc, W1, b1, W2, b2, W3, b3, W4, b4,
                       (float*)d_out);
}

// Round 5
// 125.911 us; speedup vs baseline: 1.2578x; 1.2578x over previous
//
#include <hip/hip_runtime.h>
#include <math.h>

// 64 nodes/block, grid 512 = exactly 2 blocks/CU (LDS 59.4KB -> 2 blocks).
// GEMM tiles use C=8 cols/thread where hot so LDS b128 traffic stays under
// the FMA issue rate (1 b128 per 32 FMA). All hot loops are explicitly
// software-pipelined: next j-quad's weights (global, vmcnt) and activations
// (LDS, lgkmcnt) are loaded into a second register buffer before the current
// quad's FMAs. Round-4 lesson: FMA:weight-load ratio and load latency
// coverage dominate; bank conflicts are noise (<1%).
constexpr int SV  = 100;  // V  [64][96]
constexpr int SC  = 132;  // C  [64][128]
constexpr int SH1 = 68;   // H1 [64][64]
constexpr int SH2 = 36;   // H2 [64][32]
constexpr int SH3 = 20;   // H3 [64][16]

__global__ __launch_bounds__(256, 2)
void flatnet_fused(const float* __restrict__ pgi,
                   const float* __restrict__ Wl, const float* __restrict__ bl,
                   const float* __restrict__ Wc, const float* __restrict__ bc,
                   const float* __restrict__ W1, const float* __restrict__ b1,
                   const float* __restrict__ W2, const float* __restrict__ b2,
                   const float* __restrict__ W3, const float* __restrict__ b3,
                   const float* __restrict__ W4, const float* __restrict__ b4,
                   float* __restrict__ out)
{
    __shared__ float sA[64 * SV];   // V  -> H1 -> H3
    __shared__ float sB[64 * SC];   // C  -> H2

    const int t   = threadIdx.x;
    const int blk = blockIdx.x;

    // ===== Phase 0: lift (3->32) + ring-group max (pre-act), leaky after =====
    // 4 threads/node, q = dim-quarter; each thread scans all 64 points.
    {
        const int ln = t >> 2;          // local node 0..63
        const int q  = t & 3;           // dims q*8 .. q*8+7
        const int gn = blk * 64 + ln;
        const int b  = gn >> 10;
        const int g  = gn & 1023;
        const int gi = g >> 5, gj = g & 31;

        float w0[8], w1[8], w2[8], bb[8];
        #pragma unroll
        for (int d = 0; d < 8; ++d) {
            const int dd = q * 8 + d;
            w0[d] = Wl[dd];
            w1[d] = Wl[32 + dd];
            w2[d] = Wl[64 + dd];
            bb[d] = bl[dd];
        }

        float gm[3][8];
        #pragma unroll
        for (int gg = 0; gg < 3; ++gg)
            #pragma unroll
            for (int d = 0; d < 8; ++d) gm[gg][d] = -INFINITY;

        constexpr int GT[8][8] = {
            {2,2,2,2,2,2,2,2},
            {2,2,2,2,2,2,2,2},
            {2,2,1,1,1,1,2,2},
            {2,2,1,0,0,1,2,2},
            {2,2,1,0,0,1,2,2},
            {2,2,1,1,1,1,2,2},
            {2,2,2,2,2,2,2,2},
            {2,2,2,2,2,2,2,2},
        };

        const size_t rowbase = (size_t)b * 65536 + ((size_t)gi * 8) * 256 + (size_t)gj * 8;
        #pragma unroll
        for (int pi = 0; pi < 8; ++pi) {
            const float4* src = (const float4*)(pgi + (rowbase + (size_t)pi * 256) * 3);
            float f[24];
            #pragma unroll
            for (int l = 0; l < 6; ++l) {
                const float4 v = src[l];
                f[l*4+0] = v.x; f[l*4+1] = v.y; f[l*4+2] = v.z; f[l*4+3] = v.w;
            }
            #pragma unroll
            for (int pj = 0; pj < 8; ++pj) {
                const int grp = GT[pi][pj];
                const float x = f[pj*3], y = f[pj*3+1], z = f[pj*3+2];
                #pragma unroll
                for (int d = 0; d < 8; ++d) {
                    float v = fmaf(x, w0[d], bb[d]);
                    v = fmaf(y, w1[d], v);
                    v = fmaf(z, w2[d], v);
                    gm[grp][d] = fmaxf(gm[grp][d], v);   // max BEFORE activation (monotone)
                }
            }
        }
        #pragma unroll
        for (int gg = 0; gg < 3; ++gg) {
            float4 lo, hi;
            lo.x = fmaxf(gm[gg][0], 0.2f*gm[gg][0]);
            lo.y = fmaxf(gm[gg][1], 0.2f*gm[gg][1]);
            lo.z = fmaxf(gm[gg][2], 0.2f*gm[gg][2]);
            lo.w = fmaxf(gm[gg][3], 0.2f*gm[gg][3]);
            hi.x = fmaxf(gm[gg][4], 0.2f*gm[gg][4]);
            hi.y = fmaxf(gm[gg][5], 0.2f*gm[gg][5]);
            hi.z = fmaxf(gm[gg][6], 0.2f*gm[gg][6]);
            hi.w = fmaxf(gm[gg][7], 0.2f*gm[gg][7]);
            *(float4*)&sA[ln*SV + gg*32 + q*8]     = lo;
            *(float4*)&sA[ln*SV + gg*32 + q*8 + 4] = hi;
        }
    }

    // ===== Phase 1: C = leaky(V[64,96] @ Wc[96,128] + bc); tile 4 rows x 8 cols =====
    const int p1r0 = (t >> 4) << 2;    // rows p1r0..p1r0+3
    const int p1c0 = (t & 15) << 3;    // cols p1c0..p1c0+7

    // prefetch j=0..3 weights + bias BEFORE the barrier (no LDS dependency);
    // the barrier's vmcnt(0) drain completes them "for free".
    float4 w0c[4], w1c[4];
    #pragma unroll
    for (int jj = 0; jj < 4; ++jj) {
        w0c[jj] = *(const float4*)&Wc[jj*128 + p1c0];
        w1c[jj] = *(const float4*)&Wc[jj*128 + p1c0 + 4];
    }
    float acc1[4][8];
    {
        const float4 bv0 = *(const float4*)&bc[p1c0];
        const float4 bv1 = *(const float4*)&bc[p1c0 + 4];
        #pragma unroll
        for (int r = 0; r < 4; ++r) {
            acc1[r][0]=bv0.x; acc1[r][1]=bv0.y; acc1[r][2]=bv0.z; acc1[r][3]=bv0.w;
            acc1[r][4]=bv1.x; acc1[r][5]=bv1.y; acc1[r][6]=bv1.z; acc1[r][7]=bv1.w;
        }
    }
    __syncthreads();

    {
        float4 a_c[4];
        #pragma unroll
        for (int r = 0; r < 4; ++r) a_c[r] = *(const float4*)&sA[(p1r0+r)*SV];

        for (int j = 0; j < 96; j += 4) {
            const int jn = (j + 4 < 96) ? (j + 4) : 0;   // branchless tail
            float4 a_n[4], w0n[4], w1n[4];
            #pragma unroll
            for (int jj = 0; jj < 4; ++jj) {
                w0n[jj] = *(const float4*)&Wc[(jn+jj)*128 + p1c0];
                w1n[jj] = *(const float4*)&Wc[(jn+jj)*128 + p1c0 + 4];
            }
            #pragma unroll
            for (int r = 0; r < 4; ++r) a_n[r] = *(const float4*)&sA[(p1r0+r)*SV + jn];

            #pragma unroll
            for (int jj = 0; jj < 4; ++jj) {
                const float4 wl = w0c[jj], wh = w1c[jj];
                const float wv[8] = {wl.x,wl.y,wl.z,wl.w,wh.x,wh.y,wh.z,wh.w};
                #pragma unroll
                for (int r = 0; r < 4; ++r) {
                    const float av = (jj==0)?a_c[r].x:(jj==1)?a_c[r].y:(jj==2)?a_c[r].z:a_c[r].w;
                    #pragma unroll
                    for (int c = 0; c < 8; ++c)
                        acc1[r][c] = fmaf(av, wv[c], acc1[r][c]);
                }
            }
            #pragma unroll
            for (int r = 0; r < 4; ++r) a_c[r] = a_n[r];
            #pragma unroll
            for (int jj = 0; jj < 4; ++jj) { w0c[jj] = w0n[jj]; w1c[jj] = w1n[jj]; }
        }
        #pragma unroll
        for (int r = 0; r < 4; ++r) {
            float4 lo, hi;
            lo.x = fmaxf(acc1[r][0], 0.2f*acc1[r][0]);
            lo.y = fmaxf(acc1[r][1], 0.2f*acc1[r][1]);
            lo.z = fmaxf(acc1[r][2], 0.2f*acc1[r][2]);
            lo.w = fmaxf(acc1[r][3], 0.2f*acc1[r][3]);
            hi.x = fmaxf(acc1[r][4], 0.2f*acc1[r][4]);
            hi.y = fmaxf(acc1[r][5], 0.2f*acc1[r][5]);
            hi.z = fmaxf(acc1[r][6], 0.2f*acc1[r][6]);
            hi.w = fmaxf(acc1[r][7], 0.2f*acc1[r][7]);
            *(float4*)&sB[(p1r0+r)*SC + p1c0]     = lo;
            *(float4*)&sB[(p1r0+r)*SC + p1c0 + 4] = hi;
        }
    }
    __syncthreads();

    // ===== Phase 2: H1 = relu(C[64,128] @ W1[128,64] + b1); tile 2 x 8 =====
    {
        const int r0 = (t >> 3) << 1;   // rows r0, r0+1
        const int c0 = (t & 7) << 3;    // cols c0..c0+7
        float acc[2][8];
        {
            const float4 bv0 = *(const float4*)&b1[c0];
            const float4 bv1 = *(const float4*)&b1[c0 + 4];
            #pragma unroll
            for (int r = 0; r < 2; ++r) {
                acc[r][0]=bv0.x; acc[r][1]=bv0.y; acc[r][2]=bv0.z; acc[r][3]=bv0.w;
                acc[r][4]=bv1.x; acc[r][5]=bv1.y; acc[r][6]=bv1.z; acc[r][7]=bv1.w;
            }
        }
        float4 w0c2[4], w1c2[4], a_c[2];
        #pragma unroll
        for (int jj = 0; jj < 4; ++jj) {
            w0c2[jj] = *(const float4*)&W1[jj*64 + c0];
            w1c2[jj] = *(const float4*)&W1[jj*64 + c0 + 4];
        }
        #pragma unroll
        for (int r = 0; r < 2; ++r) a_c[r] = *(const float4*)&sB[(r0+r)*SC];

        for (int j = 0; j < 128; j += 4) {
            const int jn = (j + 4 < 128) ? (j + 4) : 0;
            float4 a_n[2], w0n[4], w1n[4];
            #pragma unroll
            for (int jj = 0; jj < 4; ++jj) {
                w0n[jj] = *(const float4*)&W1[(jn+jj)*64 + c0];
                w1n[jj] = *(const float4*)&W1[(jn+jj)*64 + c0 + 4];
            }
            #pragma unroll
            for (int r = 0; r < 2; ++r) a_n[r] = *(const float4*)&sB[(r0+r)*SC + jn];

            #pragma unroll
            for (int jj = 0; jj < 4; ++jj) {
                const float4 wl = w0c2[jj], wh = w1c2[jj];
                const float wv[8] = {wl.x,wl.y,wl.z,wl.w,wh.x,wh.y,wh.z,wh.w};
                #pragma unroll
                for (int r = 0; r < 2; ++r) {
                    const float av = (jj==0)?a_c[r].x:(jj==1)?a_c[r].y:(jj==2)?a_c[r].z:a_c[r].w;
                    #pragma unroll
                    for (int c = 0; c < 8; ++c)
                        acc[r][c] = fmaf(av, wv[c], acc[r][c]);
                }
            }
            #pragma unroll
            for (int r = 0; r < 2; ++r) a_c[r] = a_n[r];
            #pragma unroll
            for (int jj = 0; jj < 4; ++jj) { w0c2[jj] = w0n[jj]; w1c2[jj] = w1n[jj]; }
        }
        #pragma unroll
        for (int r = 0; r < 2; ++r) {
            float4 lo, hi;
            lo.x = fmaxf(acc[r][0], 0.f); lo.y = fmaxf(acc[r][1], 0.f);
            lo.z = fmaxf(acc[r][2], 0.f); lo.w = fmaxf(acc[r][3], 0.f);
            hi.x = fmaxf(acc[r][4], 0.f); hi.y = fmaxf(acc[r][5], 0.f);
            hi.z = fmaxf(acc[r][6], 0.f); hi.w = fmaxf(acc[r][7], 0.f);
            *(float4*)&sA[(r0+r)*SH1 + c0]     = lo;
            *(float4*)&sA[(r0+r)*SH1 + c0 + 4] = hi;
        }
    }
    __syncthreads();

    // ===== Phase 3: H2 = relu(H1[64,64] @ W2[64,32] + b2); tile 2 x 4 =====
    {
        const int r0 = (t >> 3) << 1;   // rows r0, r0+1
        const int c0 = (t & 7) << 2;    // cols c0..c0+3
        float acc[2][4];
        {
            const float4 bv = *(const float4*)&b2[c0];
            #pragma unroll
            for (int r = 0; r < 2; ++r) { acc[r][0]=bv.x; acc[r][1]=bv.y; acc[r][2]=bv.z; acc[r][3]=bv.w; }
        }
        float4 wc3[4], a_c[2];
        #pragma unroll
        for (int jj = 0; jj < 4; ++jj) wc3[jj] = *(const float4*)&W2[jj*32 + c0];
        #pragma unroll
        for (int r = 0; r < 2; ++r) a_c[r] = *(const float4*)&sA[(r0+r)*SH1];

        for (int j = 0; j < 64; j += 4) {
            const int jn = (j + 4 < 64) ? (j + 4) : 0;
            float4 a_n[2], wn[4];
            #pragma unroll
            for (int jj = 0; jj < 4; ++jj) wn[jj] = *(const float4*)&W2[(jn+jj)*32 + c0];
            #pragma unroll
            for (int r = 0; r < 2; ++r) a_n[r] = *(const float4*)&sA[(r0+r)*SH1 + jn];

            #pragma unroll
            for (int jj = 0; jj < 4; ++jj) {
                const float4 w = wc3[jj];
                #pragma unroll
                for (int r = 0; r < 2; ++r) {
                    const float av = (jj==0)?a_c[r].x:(jj==1)?a_c[r].y:(jj==2)?a_c[r].z:a_c[r].w;
                    acc[r][0] = fmaf(av, w.x, acc[r][0]);
                    acc[r][1] = fmaf(av, w.y, acc[r][1]);
                    acc[r][2] = fmaf(av, w.z, acc[r][2]);
                    acc[r][3] = fmaf(av, w.w, acc[r][3]);
                }
            }
            #pragma unroll
            for (int r = 0; r < 2; ++r) a_c[r] = a_n[r];
            #pragma unroll
            for (int jj = 0; jj < 4; ++jj) wc3[jj] = wn[jj];
        }
        #pragma unroll
        for (int r = 0; r < 2; ++r) {
            float4 o;
            o.x = fmaxf(acc[r][0], 0.f); o.y = fmaxf(acc[r][1], 0.f);
            o.z = fmaxf(acc[r][2], 0.f); o.w = fmaxf(acc[r][3], 0.f);
            *(float4*)&sB[(r0+r)*SH2 + c0] = o;
        }
    }
    __syncthreads();

    // ===== Phase 4: H3 = relu(H2[64,32] @ W3[32,16] + b3); tile 1 x 4 =====
    {
        const int r  = t >> 2;          // 0..63
        const int c0 = (t & 3) << 2;    // cols c0..c0+3
        float acc[4];
        {
            const float4 bv = *(const float4*)&b3[c0];
            acc[0]=bv.x; acc[1]=bv.y; acc[2]=bv.z; acc[3]=bv.w;
        }
        #pragma unroll
        for (int j = 0; j < 32; j += 4) {
            const float4 A = *(const float4*)&sB[r*SH2 + j];
            const float af[4] = {A.x, A.y, A.z, A.w};
            #pragma unroll
            for (int jj = 0; jj < 4; ++jj) {
                const float4 w = *(const float4*)&W3[(j+jj)*16 + c0];
                acc[0] = fmaf(af[jj], w.x, acc[0]);
                acc[1] = fmaf(af[jj], w.y, acc[1]);
                acc[2] = fmaf(af[jj], w.z, acc[2]);
                acc[3] = fmaf(af[jj], w.w, acc[3]);
            }
        }
        float4 o;
        o.x = fmaxf(acc[0], 0.f); o.y = fmaxf(acc[1], 0.f);
        o.z = fmaxf(acc[2], 0.f); o.w = fmaxf(acc[3], 0.f);
        *(float4*)&sA[r*SH3 + c0] = o;
    }
    __syncthreads();

    // ===== Phase 5: out = H3[64,16] @ W4[16,3] + b4 =====
    if (t < 64) {
        float acc0 = b4[0], acc1 = b4[1], acc2 = b4[2];
        float a[16];
        #pragma unroll
        for (int l = 0; l < 4; ++l) {
            const float4 v = *(const float4*)&sA[t*SH3 + l*4];
            a[l*4+0]=v.x; a[l*4+1]=v.y; a[l*4+2]=v.z; a[l*4+3]=v.w;
        }
        #pragma unroll
        for (int j = 0; j < 16; ++j) {
            acc0 = fmaf(a[j], W4[j*3+0], acc0);
            acc1 = fmaf(a[j], W4[j*3+1], acc1);
            acc2 = fmaf(a[j], W4[j*3+2], acc2);
        }
        const size_t gn = (size_t)blk * 64 + t;
        out[gn*3 + 0] = acc0;
        out[gn*3 + 1] = acc1;
        out[gn*3 + 2] = acc2;
    }
}

extern "C" void kernel_launch(void* const* d_in, const int* in_sizes, int n_in,
                              void* d_out, int out_size, void* d_ws, size_t ws_size,
                              hipStream_t stream)
{
    const float* pgi = (const float*)d_in[0];
    const float* Wl  = (const float*)d_in[1];
    const float* bl  = (const float*)d_in[2];
    const float* Wc  = (const float*)d_in[3];
    const float* bc  = (const float*)d_in[4];
    const float* W1  = (const float*)d_in[5];
    const float* b1  = (const float*)d_in[6];
    const float* W2  = (const float*)d_in[7];
    const float* b2  = (const float*)d_in[8];
    const float* W3  = (const float*)d_in[9];
    const float* b3  = (const float*)d_in[10];
    const float* W4  = (const float*)d_in[11];
    const float* b4  = (const float*)d_in[12];

    hipLaunchKernelGGL(flatnet_fused, dim3(512), dim3(256), 0, stream,
                       pgi, Wl, bl, Wc, bc, W1, b1, W2, b2, W3, b3, W4, b4,
                       (float*)d_out);
}

// Round 6
// 100.951 us; speedup vs baseline: 1.5688x; 1.2473x over previous
//
#include <hip/hip_runtime.h>
#include <math.h>

// fp16-MFMA rewrite. Lift stays fp32 VALU; phases 1-4 are
// v_mfma_f32_16x16x32_f16 (fp32 accumulate, fp16 inputs only).
// All MFMA operands come from LDS as single ds_read_b128:
//  - activations X[row][k] fp16, padded strides (uniform 2-way banks = free)
//  - weights stored TRANSPOSED Wt[n][k] fp16 so B-frags are contiguous.
// Frag layouts (verified m89/m91/m120): A[m=lane&15][k=(lane>>4)*8+j],
// B[k=(lane>>4)*8+j][n=lane&15], D: row=(lane>>4)*4+reg, col=lane&15.
// LDS is one 56KB arena, aliased per phase (2 blocks/CU).

typedef _Float16 h8  __attribute__((ext_vector_type(8)));
typedef _Float16 h2t __attribute__((ext_vector_type(2)));
typedef float    f4  __attribute__((ext_vector_type(4)));

// fp16-element strides (byte stride %16==0, uniform bank spread)
constexpr int SVH = 104;  // V   [64][96]
constexpr int SWC = 104;  // Wct [128][96]
constexpr int SCH = 136;  // C   [64][128], W1t [64][128]
constexpr int S1H = 72;   // H1  [64][64],  W2t [32][64]
constexpr int S2H = 40;   // H2  [64][32],  W3t [16][32]
constexpr int S3H = 24;   // H3  [64][16]

// arena offsets (bytes)
constexpr int OFF_V = 0;        // V -> H1                (13312 B)
constexpr int OFF_W = 13312;    // Wct -> W1t/W2t/W3t     (26624 B)
constexpr int OFF_C = 39936;    // C -> H2,H3             (17408 B)
// W-region sub-offsets (fp16 elems relative to OFF_W)
constexpr int W1T_O = 0;        // 64*136 = 8704
constexpr int W2T_O = 8704;     // 32*72  = 2304
constexpr int W3T_O = 11008;    // 16*40  = 640

__global__ __launch_bounds__(256, 2)
void flatnet_fused(const float* __restrict__ pgi,
                   const float* __restrict__ Wl, const float* __restrict__ bl,
                   const float* __restrict__ Wc, const float* __restrict__ bc,
                   const float* __restrict__ W1, const float* __restrict__ b1,
                   const float* __restrict__ W2, const float* __restrict__ b2,
                   const float* __restrict__ W3, const float* __restrict__ b3,
                   const float* __restrict__ W4, const float* __restrict__ b4,
                   float* __restrict__ out)
{
    __shared__ __align__(16) char lds[57344];
    _Float16* sV = (_Float16*)(lds + OFF_V);
    _Float16* sW = (_Float16*)(lds + OFF_W);
    _Float16* sC = (_Float16*)(lds + OFF_C);

    const int t    = threadIdx.x;
    const int blk  = blockIdx.x;
    const int lane = t & 63;
    const int wv   = t >> 6;        // wave 0..3
    const int l15  = lane & 15;
    const int lq   = lane >> 4;     // 0..3

    // ===== Phase 0: lift (3->32) fp32 + ring-group max (pre-act), leaky after,
    //        fp16 store; PLUS cooperative Wc -> Wct[n][k] fp16 staging. =====
    {
        const int ln = t >> 2;          // local node 0..63
        const int q  = t & 3;           // dims q*8..q*8+7
        const int gn = blk * 64 + ln;
        const int b  = gn >> 10;
        const int g  = gn & 1023;
        const int gi = g >> 5, gj = g & 31;

        float w0[8], w1[8], w2[8], bb[8];
        #pragma unroll
        for (int d = 0; d < 8; ++d) {
            const int dd = q * 8 + d;
            w0[d] = Wl[dd];
            w1[d] = Wl[32 + dd];
            w2[d] = Wl[64 + dd];
            bb[d] = bl[dd];
        }

        float gm[3][8];
        #pragma unroll
        for (int gg = 0; gg < 3; ++gg)
            #pragma unroll
            for (int d = 0; d < 8; ++d) gm[gg][d] = -INFINITY;

        constexpr int GT[8][8] = {
            {2,2,2,2,2,2,2,2},
            {2,2,2,2,2,2,2,2},
            {2,2,1,1,1,1,2,2},
            {2,2,1,0,0,1,2,2},
            {2,2,1,0,0,1,2,2},
            {2,2,1,1,1,1,2,2},
            {2,2,2,2,2,2,2,2},
            {2,2,2,2,2,2,2,2},
        };

        const size_t rowbase = (size_t)b * 65536 + ((size_t)gi * 8) * 256 + (size_t)gj * 8;
        #pragma unroll
        for (int pi = 0; pi < 8; ++pi) {
            const float4* src = (const float4*)(pgi + (rowbase + (size_t)pi * 256) * 3);
            float f[24];
            #pragma unroll
            for (int l = 0; l < 6; ++l) {
                const float4 v = src[l];
                f[l*4+0] = v.x; f[l*4+1] = v.y; f[l*4+2] = v.z; f[l*4+3] = v.w;
            }
            #pragma unroll
            for (int pj = 0; pj < 8; ++pj) {
                const int grp = GT[pi][pj];
                const float x = f[pj*3], y = f[pj*3+1], z = f[pj*3+2];
                #pragma unroll
                for (int d = 0; d < 8; ++d) {
                    float v = fmaf(x, w0[d], bb[d]);
                    v = fmaf(y, w1[d], v);
                    v = fmaf(z, w2[d], v);
                    gm[grp][d] = fmaxf(gm[grp][d], v);
                }
            }
        }
        #pragma unroll
        for (int gg = 0; gg < 3; ++gg) {
            h8 hv;
            #pragma unroll
            for (int d = 0; d < 8; ++d) {
                const float v = gm[gg][d];
                hv[d] = (_Float16)fmaxf(v, 0.2f * v);
            }
            *(h8*)&sV[ln*SVH + gg*32 + q*8] = hv;
        }

        // stage Wc[96,128] -> Wct[n][k] fp16 (units of 2k x 4n)
        #pragma unroll
        for (int i = 0; i < 6; ++i) {
            const int u = t + (i << 8);          // 0..1535
            const int k = (u >> 5) << 1;         // 0..94 even
            const int n = (u & 31) << 2;         // 0..124
            const float4 r0 = *(const float4*)&Wc[k*128 + n];
            const float4 r1 = *(const float4*)&Wc[(k+1)*128 + n];
            h2t p0 = {(_Float16)r0.x, (_Float16)r1.x};
            h2t p1 = {(_Float16)r0.y, (_Float16)r1.y};
            h2t p2 = {(_Float16)r0.z, (_Float16)r1.z};
            h2t p3 = {(_Float16)r0.w, (_Float16)r1.w};
            *(h2t*)&sW[(n+0)*SWC + k] = p0;
            *(h2t*)&sW[(n+1)*SWC + k] = p1;
            *(h2t*)&sW[(n+2)*SWC + k] = p2;
            *(h2t*)&sW[(n+3)*SWC + k] = p3;
        }
    }
    __syncthreads();

    // ===== Phase 1 (MFMA): C = leaky(V[64,96] @ Wc[96,128] + bc) =====
    // wave wv -> N-tiles {2wv, 2wv+1}; all 4 M-tiles; K = 3 steps.
    {
        const int nt0 = wv * 2;
        h8 Bf[2][3];
        float bcv[2];
        #pragma unroll
        for (int nn = 0; nn < 2; ++nn) {
            bcv[nn] = bc[(nt0+nn)*16 + l15];
            #pragma unroll
            for (int kq = 0; kq < 3; ++kq)
                Bf[nn][kq] = *(const h8*)&sW[((nt0+nn)*16 + l15)*SWC + kq*32 + lq*8];
        }
        f4 acc[4][2];
        #pragma unroll
        for (int mt = 0; mt < 4; ++mt)
            #pragma unroll
            for (int nn = 0; nn < 2; ++nn) {
                f4 z = {bcv[nn], bcv[nn], bcv[nn], bcv[nn]};
                acc[mt][nn] = z;
            }
        #pragma unroll
        for (int mt = 0; mt < 4; ++mt) {
            h8 Af[3];
            #pragma unroll
            for (int kq = 0; kq < 3; ++kq)
                Af[kq] = *(const h8*)&sV[(mt*16 + l15)*SVH + kq*32 + lq*8];
            #pragma unroll
            for (int kq = 0; kq < 3; ++kq) {
                acc[mt][0] = __builtin_amdgcn_mfma_f32_16x16x32_f16(Af[kq], Bf[0][kq], acc[mt][0], 0, 0, 0);
                acc[mt][1] = __builtin_amdgcn_mfma_f32_16x16x32_f16(Af[kq], Bf[1][kq], acc[mt][1], 0, 0, 0);
            }
        }
        __syncthreads();   // all Wct reads done -> W region reusable

        // epilogue: leaky + fp16 scatter into C[64][128]
        #pragma unroll
        for (int mt = 0; mt < 4; ++mt)
            #pragma unroll
            for (int nn = 0; nn < 2; ++nn) {
                const int col = (nt0+nn)*16 + l15;
                #pragma unroll
                for (int r = 0; r < 4; ++r) {
                    const int row = mt*16 + lq*4 + r;
                    const float v = acc[mt][nn][r];
                    sC[row*SCH + col] = (_Float16)fmaxf(v, 0.2f * v);
                }
            }
    }

    // ===== Stage W1t/W2t/W3t fp16 into the (now free) W region =====
    {
        // W1[128,64] -> W1t[n][k], 4 units/thread
        #pragma unroll
        for (int i = 0; i < 4; ++i) {
            const int u = t + (i << 8);          // 0..1023
            const int k = (u >> 4) << 1;         // 0..126
            const int n = (u & 15) << 2;         // 0..60
            const float4 r0 = *(const float4*)&W1[k*64 + n];
            const float4 r1 = *(const float4*)&W1[(k+1)*64 + n];
            h2t p0 = {(_Float16)r0.x, (_Float16)r1.x};
            h2t p1 = {(_Float16)r0.y, (_Float16)r1.y};
            h2t p2 = {(_Float16)r0.z, (_Float16)r1.z};
            h2t p3 = {(_Float16)r0.w, (_Float16)r1.w};
            *(h2t*)&sW[W1T_O + (n+0)*SCH + k] = p0;
            *(h2t*)&sW[W1T_O + (n+1)*SCH + k] = p1;
            *(h2t*)&sW[W1T_O + (n+2)*SCH + k] = p2;
            *(h2t*)&sW[W1T_O + (n+3)*SCH + k] = p3;
        }
        // W2[64,32] -> W2t, 1 unit/thread
        {
            const int k = (t >> 3) << 1;         // 0..62
            const int n = (t & 7) << 2;          // 0..28
            const float4 r0 = *(const float4*)&W2[k*32 + n];
            const float4 r1 = *(const float4*)&W2[(k+1)*32 + n];
            h2t p0 = {(_Float16)r0.x, (_Float16)r1.x};
            h2t p1 = {(_Float16)r0.y, (_Float16)r1.y};
            h2t p2 = {(_Float16)r0.z, (_Float16)r1.z};
            h2t p3 = {(_Float16)r0.w, (_Float16)r1.w};
            *(h2t*)&sW[W2T_O + (n+0)*S1H + k] = p0;
            *(h2t*)&sW[W2T_O + (n+1)*S1H + k] = p1;
            *(h2t*)&sW[W2T_O + (n+2)*S1H + k] = p2;
            *(h2t*)&sW[W2T_O + (n+3)*S1H + k] = p3;
        }
        // W3[32,16] -> W3t, threads 0..63
        if (t < 64) {
            const int k = (t >> 2) << 1;         // 0..30
            const int n = (t & 3) << 2;          // 0..12
            const float4 r0 = *(const float4*)&W3[k*16 + n];
            const float4 r1 = *(const float4*)&W3[(k+1)*16 + n];
            h2t p0 = {(_Float16)r0.x, (_Float16)r1.x};
            h2t p1 = {(_Float16)r0.y, (_Float16)r1.y};
            h2t p2 = {(_Float16)r0.z, (_Float16)r1.z};
            h2t p3 = {(_Float16)r0.w, (_Float16)r1.w};
            *(h2t*)&sW[W3T_O + (n+0)*S2H + k] = p0;
            *(h2t*)&sW[W3T_O + (n+1)*S2H + k] = p1;
            *(h2t*)&sW[W3T_O + (n+2)*S2H + k] = p2;
            *(h2t*)&sW[W3T_O + (n+3)*S2H + k] = p3;
        }
    }
    __syncthreads();

    // ===== Phase 2 (MFMA): H1 = relu(C[64,128] @ W1[128,64] + b1) =====
    // wave wv -> N-tile wv; all 4 M-tiles; K = 4 steps.
    {
        h8 Bf[4];
        #pragma unroll
        for (int kq = 0; kq < 4; ++kq)
            Bf[kq] = *(const h8*)&sW[W1T_O + (wv*16 + l15)*SCH + kq*32 + lq*8];
        const float bv = b1[wv*16 + l15];
        f4 acc[4];
        #pragma unroll
        for (int mt = 0; mt < 4; ++mt) { f4 z = {bv,bv,bv,bv}; acc[mt] = z; }
        #pragma unroll
        for (int mt = 0; mt < 4; ++mt) {
            #pragma unroll
            for (int kq = 0; kq < 4; ++kq) {
                const h8 Af = *(const h8*)&sC[(mt*16 + l15)*SCH + kq*32 + lq*8];
                acc[mt] = __builtin_amdgcn_mfma_f32_16x16x32_f16(Af, Bf[kq], acc[mt], 0, 0, 0);
            }
        }
        __syncthreads();   // C reads done; V region reusable for H1
        #pragma unroll
        for (int mt = 0; mt < 4; ++mt) {
            const int col = wv*16 + l15;
            #pragma unroll
            for (int r = 0; r < 4; ++r) {
                const int row = mt*16 + lq*4 + r;
                sV[row*S1H + col] = (_Float16)fmaxf(acc[mt][r], 0.f);
            }
        }
    }
    __syncthreads();

    // ===== Phase 3 (MFMA): H2 = relu(H1[64,64] @ W2[64,32] + b2) =====
    // 8 tiles: wave wv -> nt = wv&1, mt in {(wv>>1)*2, +1}; K = 2 steps.
    {
        const int nt  = wv & 1;
        const int mt0 = (wv >> 1) << 1;
        h8 Bf[2];
        #pragma unroll
        for (int kq = 0; kq < 2; ++kq)
            Bf[kq] = *(const h8*)&sW[W2T_O + (nt*16 + l15)*S1H + kq*32 + lq*8];
        const float bv = b2[nt*16 + l15];
        f4 acc[2];
        #pragma unroll
        for (int mi = 0; mi < 2; ++mi) { f4 z = {bv,bv,bv,bv}; acc[mi] = z; }
        #pragma unroll
        for (int mi = 0; mi < 2; ++mi) {
            #pragma unroll
            for (int kq = 0; kq < 2; ++kq) {
                const h8 Af = *(const h8*)&sV[((mt0+mi)*16 + l15)*S1H + kq*32 + lq*8];
                acc[mi] = __builtin_amdgcn_mfma_f32_16x16x32_f16(Af, Bf[kq], acc[mi], 0, 0, 0);
            }
        }
        __syncthreads();   // C region fully dead -> H2 can be written
        #pragma unroll
        for (int mi = 0; mi < 2; ++mi) {
            const int col = nt*16 + l15;
            #pragma unroll
            for (int r = 0; r < 4; ++r) {
                const int row = (mt0+mi)*16 + lq*4 + r;
                sC[row*S2H + col] = (_Float16)fmaxf(acc[mi][r], 0.f);
            }
        }
    }
    __syncthreads();

    // ===== Phase 4 (MFMA): H3 = relu(H2[64,32] @ W3[32,16] + b3) =====
    // wave wv -> M-tile wv; single N-tile, single K step.
    {
        const h8 Bf = *(const h8*)&sW[W3T_O + l15*S2H + lq*8];
        const float bv = b3[l15];
        f4 acc = {bv,bv,bv,bv};
        const h8 Af = *(const h8*)&sC[(wv*16 + l15)*S2H + lq*8];
        acc = __builtin_amdgcn_mfma_f32_16x16x32_f16(Af, Bf, acc, 0, 0, 0);
        #pragma unroll
        for (int r = 0; r < 4; ++r) {
            const int row = wv*16 + lq*4 + r;
            sC[2560 + row*S3H + l15] = (_Float16)fmaxf(acc[r], 0.f);
        }
    }
    __syncthreads();

    // ===== Phase 5: out = H3[64,16] @ W4[16,3] + b4 (fp32 VALU) =====
    if (t < 64) {
        const h8 h0 = *(const h8*)&sC[2560 + t*S3H];
        const h8 h1 = *(const h8*)&sC[2560 + t*S3H + 8];
        float a[16];
        #pragma unroll
        for (int j = 0; j < 8; ++j) { a[j] = (float)h0[j]; a[8+j] = (float)h1[j]; }
        float acc0 = b4[0], acc1 = b4[1], acc2 = b4[2];
        #pragma unroll
        for (int j = 0; j < 16; ++j) {
            acc0 = fmaf(a[j], W4[j*3+0], acc0);
            acc1 = fmaf(a[j], W4[j*3+1], acc1);
            acc2 = fmaf(a[j], W4[j*3+2], acc2);
        }
        const size_t gn = (size_t)blk * 64 + t;
        out[gn*3 + 0] = acc0;
        out[gn*3 + 1] = acc1;
        out[gn*3 + 2] = acc2;
    }
}

extern "C" void kernel_launch(void* const* d_in, const int* in_sizes, int n_in,
                              void* d_out, int out_size, void* d_ws, size_t ws_size,
                              hipStream_t stream)
{
    const float* pgi = (const float*)d_in[0];
    const float* Wl  = (const float*)d_in[1];
    const float* bl  = (const float*)d_in[2];
    const float* Wc  = (const float*)d_in[3];
    const float* bc  = (const float*)d_in[4];
    const float* W1  = (const float*)d_in[5];
    const float* b1  = (const float*)d_in[6];
    const float* W2  = (const float*)d_in[7];
    const float* b2  = (const float*)d_in[8];
    const float* W3  = (const float*)d_in[9];
    const float* b3  = (const float*)d_in[10];
    const float* W4  = (const float*)d_in[11];
    const float* b4  = (const float*)d_in[12];

    hipLaunchKernelGGL(flatnet_fused, dim3(512), dim3(256), 0, stream,
                       pgi, Wl, bl, Wc, bc, W1, b1, W2, b2, W3, b3, W4, b4,
                       (float*)d_out);
}